// Round 1
// 1100.862 us; speedup vs baseline: 1.2656x; 1.2656x over previous
//
#include <hip/hip_runtime.h>
#include <hip/hip_bf16.h>

// Problem constants (fixed by reference): B=4, S=6000, H=12, D=128, HID=1536
#define BATCH 4
#define SEQ   6000
#define NHEAD 12
#define HDIM  128
#define HID   1536
#define CHUNK 12
#define CTXW  24
#define NBLK  500            // SEQ / CHUNK
#define MROWS (BATCH * SEQ)  // 24000

#define Q_SCALE_D (0.08838834764831845 / 0.6931471805599453)   // D^-0.5 / ln2
#define K_SCALE_D (1.3132616875182228 / 0.6931471805599453)    // ln(1+e) / ln2

typedef __bf16 bf16x8 __attribute__((ext_vector_type(8)));
typedef float  floatx4 __attribute__((ext_vector_type(4)));

// Sanitizer: clamps to +-1e15 and maps NaN to -1e15.
#define SAN_LIM 1e15f
__device__ __forceinline__ float san(float f) {
    return fminf(fmaxf(f, -SAN_LIM), SAN_LIM);
}

// Async global->LDS, 16B per lane. LDS dest must be the wave-uniform base;
// HW writes lane i to base + i*16 (guide §5). Global src is per-lane.
__device__ __forceinline__ void gload16(const void* g, void* l) {
    __builtin_amdgcn_global_load_lds(
        (__attribute__((address_space(1))) void*)g,
        (__attribute__((address_space(3))) void*)l,
        16, 0, 0);
}

// ---------------------------------------------------------------------------
// qscale[d] = Q_SCALE * softplus(per_dim_scale[d])
// ---------------------------------------------------------------------------
__global__ void qscale_kernel(const float* __restrict__ pds,
                              float* __restrict__ qs) {
    int d = threadIdx.x;
    float x = san(pds[d]);
    float sp = (x > 20.0f) ? x : log1pf(expf(x));
    qs[d] = san((float)Q_SCALE_D * sp);
}

// ---------------------------------------------------------------------------
// fp32 -> bf16 conversion passes (hoists all per-tile converts out of GEMMs)
// ---------------------------------------------------------------------------
__device__ __forceinline__ void cvt4(const float* __restrict__ src,
                                     __hip_bfloat16* __restrict__ dst, int i) {
    float4 f = ((const float4*)src)[i];
    union { __hip_bfloat16 h[4]; uint2 u; } cv;
    cv.h[0] = __float2bfloat16(san(f.x));
    cv.h[1] = __float2bfloat16(san(f.y));
    cv.h[2] = __float2bfloat16(san(f.z));
    cv.h[3] = __float2bfloat16(san(f.w));
    ((uint2*)dst)[i] = cv.u;
}

__global__ void convert_x_kernel(const float* __restrict__ src,
                                 __hip_bfloat16* __restrict__ dst, int n4) {
    int stride = gridDim.x * blockDim.x;
    for (int i = blockIdx.x * blockDim.x + threadIdx.x; i < n4; i += stride)
        cvt4(src, dst, i);
}

// Converts Wq/Wk/Wv (into one concatenated [4608][1536] buffer), Wrel, Wpost,
// pos_emb. grid = (2304, 6); weight segments are exactly 2304*256 float4s.
__global__ void convert_misc_kernel(
    const float* __restrict__ Wq, const float* __restrict__ Wk,
    const float* __restrict__ Wv, const float* __restrict__ Wrel,
    const float* __restrict__ Wpost, const float* __restrict__ pos,
    __hip_bfloat16* __restrict__ Wqkv, __hip_bfloat16* __restrict__ Wrelb,
    __hip_bfloat16* __restrict__ Wpostb, __hip_bfloat16* __restrict__ posb) {
    const float* src;
    __hip_bfloat16* dst;
    int n4 = 589824;                       // 1536*1536/4
    switch (blockIdx.y) {
        case 0: src = Wq;    dst = Wqkv;            break;
        case 1: src = Wk;    dst = Wqkv + 2359296;  break;
        case 2: src = Wv;    dst = Wqkv + 4718592;  break;
        case 3: src = Wrel;  dst = Wrelb;           break;
        case 4: src = Wpost; dst = Wpostb;          break;
        default: src = pos;  dst = posb; n4 = 9216; break;  // 24*1536/4
    }
    int i = blockIdx.x * 256 + threadIdx.x;
    if (i < n4) cvt4(src, dst, i);
}

// ---------------------------------------------------------------------------
// C[M,N] = A[M,K] @ W[N,K]^T, all-bf16 inputs, m97 structure:
// 128x128 tile, BK=32, 256 thr = 4 waves, global_load_lds width-16 staging
// into linear [128][32] LDS, 4x4 16x16x32 bf16 MFMA, fp32 accum.
// QKV=1: fused 3-weight epilogue; tileN in [0,4608), z = tileN/1536 picks
// dest buffer + scale (z0: qscale[col&127], z1: K_SCALE, z2: 1).
// QKV=0: single dest C0 with row stride HID; CDT 0=bf16 / 1=fp32 store.
// ---------------------------------------------------------------------------
template<int QKV, int CDT>
__device__ __forceinline__ void gemm_bb_core(
    const __hip_bfloat16* __restrict__ A,
    const __hip_bfloat16* __restrict__ W,
    void* __restrict__ C0, void* __restrict__ C1, void* __restrict__ C2,
    int M, int K, const float* __restrict__ qscale)
{
    __shared__ __align__(16) __hip_bfloat16 As[128 * 32];
    __shared__ __align__(16) __hip_bfloat16 Bs[128 * 32];

    const int tid   = threadIdx.x;
    const int wave  = tid >> 6;
    const int lane  = tid & 63;
    const int tileM = blockIdx.y * 128;
    const int tileN = blockIdx.x * 128;

    // staging geometry: call t covers LDS bytes [t*4096 + wave*1024, +1024);
    // lane's 16B land at +lane*16 -> row = t*64 + wave*16 + lane/4,
    // col = (lane&3)*8 bf16.
    const int sr = (wave << 4) + (lane >> 2);
    const int sc = (lane & 3) << 3;
    int ar0 = tileM + sr;      if (ar0 > M - 1) ar0 = M - 1;
    int ar1 = tileM + sr + 64; if (ar1 > M - 1) ar1 = M - 1;
    const __hip_bfloat16* ag0 = A + (size_t)ar0 * K + sc;
    const __hip_bfloat16* ag1 = A + (size_t)ar1 * K + sc;
    const __hip_bfloat16* bg0 = W + (size_t)(tileN + sr) * K + sc;
    const __hip_bfloat16* bg1 = W + (size_t)(tileN + sr + 64) * K + sc;
    __hip_bfloat16* la0 = As + (wave << 9);          // wave-uniform LDS bases
    __hip_bfloat16* la1 = As + 2048 + (wave << 9);
    __hip_bfloat16* lb0 = Bs + (wave << 9);
    __hip_bfloat16* lb1 = Bs + 2048 + (wave << 9);

    const int wr   = (wave >> 1) << 6;   // wave row offset (0/64)
    const int wc   = (wave & 1) << 6;    // wave col offset (0/64)
    const int frow = lane & 15;
    const int fk   = (lane >> 4) << 3;

    floatx4 acc[4][4] = {};

    for (int k0 = 0; k0 < K; k0 += 32) {
        __syncthreads();                  // LDS reads of prev iter done
        gload16(ag0 + k0, la0);
        gload16(ag1 + k0, la1);
        gload16(bg0 + k0, lb0);
        gload16(bg1 + k0, lb1);
        __syncthreads();                  // drains vmcnt -> tiles ready

        bf16x8 af[4], bfv[4];
        #pragma unroll
        for (int i = 0; i < 4; ++i)
            af[i] = *(const bf16x8*)&As[(wr + i * 16 + frow) * 32 + fk];
        #pragma unroll
        for (int j = 0; j < 4; ++j)
            bfv[j] = *(const bf16x8*)&Bs[(wc + j * 16 + frow) * 32 + fk];
        #pragma unroll
        for (int i = 0; i < 4; ++i)
            #pragma unroll
            for (int j = 0; j < 4; ++j)
                acc[i][j] = __builtin_amdgcn_mfma_f32_16x16x32_bf16(
                    af[i], bfv[j], acc[i][j], 0, 0, 0);
    }

    // epilogue: C/D layout col=lane&15, row=(lane>>4)*4+r
    const int orow = (lane >> 4) << 2;
    if (QKV) {
        const int z = tileN / 1536;
        __hip_bfloat16* C =
            (__hip_bfloat16*)(z == 0 ? C0 : (z == 1 ? C1 : C2));
        const int cb = tileN - z * 1536 + wc;
        #pragma unroll
        for (int i = 0; i < 4; ++i) {
            #pragma unroll
            for (int r = 0; r < 4; ++r) {
                int row = tileM + wr + i * 16 + orow + r;
                if (row < M) {
                    #pragma unroll
                    for (int j = 0; j < 4; ++j) {
                        int col = cb + j * 16 + frow;
                        float v = acc[i][j][r];
                        if (z == 0)      v *= qscale[col & 127];
                        else if (z == 1) v *= (float)K_SCALE_D;
                        C[(size_t)row * HID + col] = __float2bfloat16(v);
                    }
                }
            }
        }
    } else {
        #pragma unroll
        for (int i = 0; i < 4; ++i) {
            #pragma unroll
            for (int r = 0; r < 4; ++r) {
                int row = tileM + wr + i * 16 + orow + r;
                if (row < M) {
                    #pragma unroll
                    for (int j = 0; j < 4; ++j) {
                        int col = tileN + wc + j * 16 + frow;
                        float v = acc[i][j][r];
                        if (CDT == 0)
                            ((__hip_bfloat16*)C0)[(size_t)row * HID + col] =
                                __float2bfloat16(v);
                        else
                            ((float*)C0)[(size_t)row * HID + col] = v;
                    }
                }
            }
        }
    }
}

__global__ __launch_bounds__(256, 2)
void gemm_qkv_bb(const __hip_bfloat16* __restrict__ A,
                 const __hip_bfloat16* __restrict__ W,
                 __hip_bfloat16* __restrict__ Q,
                 __hip_bfloat16* __restrict__ Kb,
                 __hip_bfloat16* __restrict__ V,
                 const float* __restrict__ qscale, int M) {
    gemm_bb_core<1, 0>(A, W, Q, Kb, V, M, HID, qscale);
}

__global__ __launch_bounds__(256, 2)
void gemm_rel(const __hip_bfloat16* __restrict__ A,
              const __hip_bfloat16* __restrict__ W,
              __hip_bfloat16* __restrict__ C, int M) {
    gemm_bb_core<0, 0>(A, W, C, C, C, M, HID, nullptr);
}

__global__ __launch_bounds__(256, 2)
void gemm_post(const __hip_bfloat16* __restrict__ A,
               const __hip_bfloat16* __restrict__ W,
               float* __restrict__ C, int M) {
    gemm_bb_core<0, 1>(A, W, C, C, C, M, HID, nullptr);
}

// ---------------------------------------------------------------------------
// Attention: one block per (b_local, chunk n, head h). All buffers bf16.
// ---------------------------------------------------------------------------
__global__ __launch_bounds__(256)
void attn_kernel(const __hip_bfloat16* __restrict__ Q,
                 const __hip_bfloat16* __restrict__ Kt,
                 const __hip_bfloat16* __restrict__ Vt,
                 const __hip_bfloat16* __restrict__ R,   // [24][1536] rel_k
                 __hip_bfloat16* __restrict__ O)
{
    const int tid = threadIdx.x;
    int idx = blockIdx.x;
    const int h = idx % NHEAD;  idx /= NHEAD;
    const int n = idx % NBLK;   idx /= NBLK;
    const int b = idx;                       // phase-local batch index

    __shared__ __align__(16) __hip_bfloat16 qs[CHUNK * HDIM];
    __shared__ __align__(16) __hip_bfloat16 ks[23 * HDIM];
    __shared__ __align__(16) __hip_bfloat16 vs[23 * HDIM];
    __shared__ __align__(16) __hip_bfloat16 rs[CHUNK * HDIM]; // rs[j]=rel_k[12-j]
    __shared__ float lg[CHUNK][CHUNK];

    const size_t rowbase = (size_t)b * SEQ + (size_t)n * CHUNK;
    const int hoff = h * HDIM;

    #pragma unroll
    for (int it = 0; it < 3; ++it) {
        int i = it * 256 + tid;
        int row = i >> 6;
        int cu  = i & 63;
        ((unsigned int*)qs)[i] =
            *(const unsigned int*)(Q + (rowbase + row) * HID + hoff + cu * 2);
    }
    #pragma unroll
    for (int it = 0; it < 6; ++it) {
        int i = it * 256 + tid;
        if (i < 1472) {
            int row = i >> 6;
            int cu  = i & 63;
            int g = n * CHUNK + row - 11;
            unsigned int kval = 0u, vval = 0u;
            if (g >= 0) {
                size_t off = ((size_t)b * SEQ + g) * HID + hoff + cu * 2;
                kval = *(const unsigned int*)(Kt + off);
                vval = *(const unsigned int*)(Vt + off);
            }
            ((unsigned int*)ks)[i] = kval;
            ((unsigned int*)vs)[i] = vval;
        }
    }
    #pragma unroll
    for (int it = 0; it < 3; ++it) {
        int i = it * 256 + tid;
        int j  = i >> 6;
        int cu = i & 63;
        ((unsigned int*)rs)[i] =
            *(const unsigned int*)(R + (size_t)(12 - j) * HID + hoff + cu * 2);
    }
    __syncthreads();

    if (tid < CHUNK * CHUNK) {
        int q = tid / CHUNK, j = tid % CHUNK;
        bool valid = (n > 0) || (j <= q);
        float acc = 0.0f;
        if (valid) {
            int krow = q + 11 - j;
            const __hip_bfloat16* qp = qs + q * HDIM;
            const __hip_bfloat16* kp = ks + krow * HDIM;
            const __hip_bfloat16* rp = rs + j * HDIM;
            #pragma unroll 16
            for (int d = 0; d < HDIM; ++d)
                acc += __bfloat162float(qp[d]) *
                       (__bfloat162float(kp[d]) + __bfloat162float(rp[d]));
            acc = tanhf(acc * 0.02f) * 50.0f;
        }
        lg[q][j] = valid ? acc : -1e30f;
    }
    __syncthreads();

    if (tid < CHUNK) {
        float m = -1e30f;
        #pragma unroll
        for (int j = 0; j < CHUNK; ++j) m = fmaxf(m, lg[tid][j]);
        float e[CHUNK];
        float s = 0.0f;
        #pragma unroll
        for (int j = 0; j < CHUNK; ++j) { e[j] = expf(lg[tid][j] - m); s += e[j]; }
        float inv = 1.0f / s;
        #pragma unroll
        for (int j = 0; j < CHUNK; ++j) lg[tid][j] = e[j] * inv;
    }
    __syncthreads();

    #pragma unroll
    for (int it = 0; it < 6; ++it) {
        int i = it * 256 + tid;
        int q = i >> 7, d = i & 127;
        float acc = 0.0f;
        #pragma unroll
        for (int j = 0; j < CHUNK; ++j)
            acc += lg[q][j] * __bfloat162float(vs[(q + 11 - j) * HDIM + d]);
        O[(rowbase + q) * HID + hoff + d] = __float2bfloat16(san(acc));
    }
}

// ---------------------------------------------------------------------------
// ws layout: [qscale 1KB][Rk 72KB][posb 72KB][Wqkv 13.5MB][Wrelb 4.5MB]
//            [Wpostb 4.5MB][Qb][Kb]
// Xb (bf16 copy of x) and Vb live inside d_out: for phase p they occupy the
// front/back half of phase p's own output region [p*Mp*HID*4, ...). Both are
// dead before the phase's post-GEMM writes that region; phase p+1's scratch
// never touches already-written output. Attention output O aliases Qb.
// ---------------------------------------------------------------------------
extern "C" void kernel_launch(void* const* d_in, const int* in_sizes, int n_in,
                              void* d_out, int out_size, void* d_ws, size_t ws_size,
                              hipStream_t stream) {
    const float* x     = (const float*)d_in[0];
    const float* pos   = (const float*)d_in[1];
    const float* Wq    = (const float*)d_in[2];
    const float* Wk    = (const float*)d_in[3];
    const float* Wv    = (const float*)d_in[4];
    const float* Wv_   = (const float*)d_in[4];
    const float* Wrel  = (const float*)d_in[5];
    const float* Wpost = (const float*)d_in[6];
    const float* pds   = (const float*)d_in[7];
    float* out = (float*)d_out;
    (void)Wv_;

    char* ws = (char*)d_ws;
    float* qscale          = (float*)ws;                          // 1024 B
    __hip_bfloat16* Rk     = (__hip_bfloat16*)(ws + 1024);        // 73728 B
    __hip_bfloat16* posb   = (__hip_bfloat16*)(ws + 1024 + 73728);
    __hip_bfloat16* Wqkv   = (__hip_bfloat16*)(ws + 1024 + 2 * 73728);
    __hip_bfloat16* Wrelb  = Wqkv + (size_t)3 * 1536 * 1536;
    __hip_bfloat16* Wpostb = Wrelb + (size_t)1536 * 1536;
    __hip_bfloat16* Qb     = Wpostb + (size_t)1536 * 1536;
    const size_t fixed = 1024 + 2 * 73728 +
                         (size_t)5 * 1536 * 1536 * 2;             // 23,741,440
    const size_t qk_full = 2 * (size_t)MROWS * HID * 2;           // 147,456,000

    int phases;
    if      (ws_size >= fixed + qk_full)     phases = 1;
    else if (ws_size >= fixed + qk_full / 2) phases = 2;
    else                                     phases = 4;
    const int    Bp = BATCH / phases;
    const size_t Mp = (size_t)Bp * SEQ;
    __hip_bfloat16* Kb = Qb + Mp * HID;

    qscale_kernel<<<1, 128, 0, stream>>>(pds, qscale);
    convert_misc_kernel<<<dim3(2304, 6), 256, 0, stream>>>(
        Wq, Wk, Wv, Wrel, Wpost, pos, Wqkv, Wrelb, Wpostb, posb);
    gemm_rel<<<dim3(12, 1), 256, 0, stream>>>(posb, Wrelb, Rk, CTXW);

    for (int p = 0; p < phases; ++p) {
        __hip_bfloat16* Xb =
            (__hip_bfloat16*)((char*)d_out + p * Mp * HID * 4);
        __hip_bfloat16* Vb = Xb + Mp * HID;

        convert_x_kernel<<<2048, 256, 0, stream>>>(
            x + p * Mp * HID, Xb, (int)(Mp * HID / 4));
        gemm_qkv_bb<<<dim3(36, (unsigned)((Mp + 127) / 128)), 256, 0, stream>>>(
            Xb, Wqkv, Qb, Kb, Vb, qscale, (int)Mp);
        attn_kernel<<<Bp * NBLK * NHEAD, 256, 0, stream>>>(Qb, Kb, Vb, Rk, Qb);
        gemm_post<<<dim3(12, (unsigned)((Mp + 127) / 128)), 256, 0, stream>>>(
            Qb, Wpostb, out + p * Mp * HID, (int)Mp);
    }
}

// Round 2
// 1018.755 us; speedup vs baseline: 1.3676x; 1.0806x over previous
//
#include <hip/hip_runtime.h>
#include <hip/hip_bf16.h>

// Problem constants (fixed by reference): B=4, S=6000, H=12, D=128, HID=1536
#define BATCH 4
#define SEQ   6000
#define NHEAD 12
#define HDIM  128
#define HID   1536
#define CHUNK 12
#define CTXW  24
#define NBLK  500            // SEQ / CHUNK
#define MROWS (BATCH * SEQ)  // 24000

#define Q_SCALE_D (0.08838834764831845 / 0.6931471805599453)   // D^-0.5 / ln2
#define K_SCALE_D (1.3132616875182228 / 0.6931471805599453)    // ln(1+e) / ln2

typedef __bf16 bf16x8 __attribute__((ext_vector_type(8)));
typedef float  floatx4 __attribute__((ext_vector_type(4)));
typedef unsigned short u16x8 __attribute__((ext_vector_type(8)));

// Sanitizer: clamps to +-1e15 and maps NaN to -1e15.
#define SAN_LIM 1e15f
__device__ __forceinline__ float san(float f) {
    return fminf(fmaxf(f, -SAN_LIM), SAN_LIM);
}

__device__ __forceinline__ float bf2f(unsigned short b) {
    return __uint_as_float((unsigned)b << 16);
}

// Async global->LDS, 16B per lane. LDS dest must be the wave-uniform base;
// HW writes lane i to base + i*16. Global src is per-lane.
__device__ __forceinline__ void gload16(const void* g, void* l) {
    __builtin_amdgcn_global_load_lds(
        (__attribute__((address_space(1))) void*)g,
        (__attribute__((address_space(3))) void*)l,
        16, 0, 0);
}

// ---------------------------------------------------------------------------
// qscale[d] = Q_SCALE * softplus(per_dim_scale[d])
// ---------------------------------------------------------------------------
__global__ void qscale_kernel(const float* __restrict__ pds,
                              float* __restrict__ qs) {
    int d = threadIdx.x;
    float x = san(pds[d]);
    float sp = (x > 20.0f) ? x : log1pf(expf(x));
    qs[d] = san((float)Q_SCALE_D * sp);
}

// ---------------------------------------------------------------------------
// fp32 -> bf16 conversion passes
// ---------------------------------------------------------------------------
__device__ __forceinline__ void cvt4(const float* __restrict__ src,
                                     __hip_bfloat16* __restrict__ dst, int i) {
    float4 f = ((const float4*)src)[i];
    union { __hip_bfloat16 h[4]; uint2 u; } cv;
    cv.h[0] = __float2bfloat16(san(f.x));
    cv.h[1] = __float2bfloat16(san(f.y));
    cv.h[2] = __float2bfloat16(san(f.z));
    cv.h[3] = __float2bfloat16(san(f.w));
    ((uint2*)dst)[i] = cv.u;
}

__global__ void convert_x_kernel(const float* __restrict__ src,
                                 __hip_bfloat16* __restrict__ dst, int n4) {
    int stride = gridDim.x * blockDim.x;
    for (int i = blockIdx.x * blockDim.x + threadIdx.x; i < n4; i += stride)
        cvt4(src, dst, i);
}

__global__ void convert_misc_kernel(
    const float* __restrict__ Wq, const float* __restrict__ Wk,
    const float* __restrict__ Wv, const float* __restrict__ Wrel,
    const float* __restrict__ Wpost, const float* __restrict__ pos,
    __hip_bfloat16* __restrict__ Wqkv, __hip_bfloat16* __restrict__ Wrelb,
    __hip_bfloat16* __restrict__ Wpostb, __hip_bfloat16* __restrict__ posb) {
    const float* src;
    __hip_bfloat16* dst;
    int n4 = 589824;                       // 1536*1536/4
    switch (blockIdx.y) {
        case 0: src = Wq;    dst = Wqkv;            break;
        case 1: src = Wk;    dst = Wqkv + 2359296;  break;
        case 2: src = Wv;    dst = Wqkv + 4718592;  break;
        case 3: src = Wrel;  dst = Wrelb;           break;
        case 4: src = Wpost; dst = Wpostb;          break;
        default: src = pos;  dst = posb; n4 = 9216; break;  // 24*1536/4
    }
    int i = blockIdx.x * 256 + threadIdx.x;
    if (i < n4) cvt4(src, dst, i);
}

// ---------------------------------------------------------------------------
// C[M,N] = A[M,K] @ W[N,K]^T, all-bf16, m97 structure + T1 XCD swizzle.
// T1: linear wgid remapped so each XCD gets a contiguous n-fastest chunk ->
// an A-panel lives in exactly one XCD L2; W refills hit L3.
// ---------------------------------------------------------------------------
template<int QKV, int CDT>
__device__ __forceinline__ void gemm_bb_core(
    const __hip_bfloat16* __restrict__ A,
    const __hip_bfloat16* __restrict__ W,
    void* __restrict__ C0, void* __restrict__ C1, void* __restrict__ C2,
    int M, int K, const float* __restrict__ qscale)
{
    __shared__ __align__(16) __hip_bfloat16 As[128 * 32];
    __shared__ __align__(16) __hip_bfloat16 Bs[128 * 32];

    const int tid   = threadIdx.x;
    const int wave  = tid >> 6;
    const int lane  = tid & 63;

    // T1 XCD-aware swizzle (requires nwg % 8 == 0, else identity)
    const int gx   = gridDim.x;
    const int nwg  = gx * gridDim.y;
    const int orig = blockIdx.y * gx + blockIdx.x;
    int wgid = orig;
    if ((nwg & 7) == 0)
        wgid = (orig & 7) * (nwg >> 3) + (orig >> 3);
    const int tileN = (wgid % gx) * 128;
    const int tileM = (wgid / gx) * 128;

    const int sr = (wave << 4) + (lane >> 2);
    const int sc = (lane & 3) << 3;
    int ar0 = tileM + sr;      if (ar0 > M - 1) ar0 = M - 1;
    int ar1 = tileM + sr + 64; if (ar1 > M - 1) ar1 = M - 1;
    const __hip_bfloat16* ag0 = A + (size_t)ar0 * K + sc;
    const __hip_bfloat16* ag1 = A + (size_t)ar1 * K + sc;
    const __hip_bfloat16* bg0 = W + (size_t)(tileN + sr) * K + sc;
    const __hip_bfloat16* bg1 = W + (size_t)(tileN + sr + 64) * K + sc;
    __hip_bfloat16* la0 = As + (wave << 9);
    __hip_bfloat16* la1 = As + 2048 + (wave << 9);
    __hip_bfloat16* lb0 = Bs + (wave << 9);
    __hip_bfloat16* lb1 = Bs + 2048 + (wave << 9);

    const int wr   = (wave >> 1) << 6;
    const int wc   = (wave & 1) << 6;
    const int frow = lane & 15;
    const int fk   = (lane >> 4) << 3;

    floatx4 acc[4][4] = {};

    for (int k0 = 0; k0 < K; k0 += 32) {
        __syncthreads();
        gload16(ag0 + k0, la0);
        gload16(ag1 + k0, la1);
        gload16(bg0 + k0, lb0);
        gload16(bg1 + k0, lb1);
        __syncthreads();

        bf16x8 af[4], bfv[4];
        #pragma unroll
        for (int i = 0; i < 4; ++i)
            af[i] = *(const bf16x8*)&As[(wr + i * 16 + frow) * 32 + fk];
        #pragma unroll
        for (int j = 0; j < 4; ++j)
            bfv[j] = *(const bf16x8*)&Bs[(wc + j * 16 + frow) * 32 + fk];
        #pragma unroll
        for (int i = 0; i < 4; ++i)
            #pragma unroll
            for (int j = 0; j < 4; ++j)
                acc[i][j] = __builtin_amdgcn_mfma_f32_16x16x32_bf16(
                    af[i], bfv[j], acc[i][j], 0, 0, 0);
    }

    const int orow = (lane >> 4) << 2;
    if (QKV) {
        const int z = tileN / 1536;
        __hip_bfloat16* C =
            (__hip_bfloat16*)(z == 0 ? C0 : (z == 1 ? C1 : C2));
        const int cb = tileN - z * 1536 + wc;
        #pragma unroll
        for (int i = 0; i < 4; ++i) {
            #pragma unroll
            for (int r = 0; r < 4; ++r) {
                int row = tileM + wr + i * 16 + orow + r;
                if (row < M) {
                    #pragma unroll
                    for (int j = 0; j < 4; ++j) {
                        int col = cb + j * 16 + frow;
                        float v = acc[i][j][r];
                        if (z == 0)      v *= qscale[col & 127];
                        else if (z == 1) v *= (float)K_SCALE_D;
                        C[(size_t)row * HID + col] = __float2bfloat16(v);
                    }
                }
            }
        }
    } else {
        #pragma unroll
        for (int i = 0; i < 4; ++i) {
            #pragma unroll
            for (int r = 0; r < 4; ++r) {
                int row = tileM + wr + i * 16 + orow + r;
                if (row < M) {
                    #pragma unroll
                    for (int j = 0; j < 4; ++j) {
                        int col = tileN + wc + j * 16 + frow;
                        float v = acc[i][j][r];
                        if (CDT == 0)
                            ((__hip_bfloat16*)C0)[(size_t)row * HID + col] =
                                __float2bfloat16(v);
                        else
                            ((float*)C0)[(size_t)row * HID + col] = v;
                    }
                }
            }
        }
    }
}

__global__ __launch_bounds__(256, 2)
void gemm_qkv_bb(const __hip_bfloat16* __restrict__ A,
                 const __hip_bfloat16* __restrict__ W,
                 __hip_bfloat16* __restrict__ Q,
                 __hip_bfloat16* __restrict__ Kb,
                 __hip_bfloat16* __restrict__ V,
                 const float* __restrict__ qscale, int M) {
    gemm_bb_core<1, 0>(A, W, Q, Kb, V, M, HID, qscale);
}

__global__ __launch_bounds__(256, 2)
void gemm_rel(const __hip_bfloat16* __restrict__ A,
              const __hip_bfloat16* __restrict__ W,
              __hip_bfloat16* __restrict__ C, int M) {
    gemm_bb_core<0, 0>(A, W, C, C, C, M, HID, nullptr);
}

__global__ __launch_bounds__(256, 2)
void gemm_post(const __hip_bfloat16* __restrict__ A,
               const __hip_bfloat16* __restrict__ W,
               float* __restrict__ C, int M) {
    gemm_bb_core<0, 1>(A, W, C, C, C, M, HID, nullptr);
}

// ---------------------------------------------------------------------------
// Attention: one block per (b_local, chunk n, head h). Vectorized:
//  - staging: uint4 (16B) global loads
//  - Q/K/R LDS XOR-swizzled (byte ^= (row&7)<<4; rows are 256B) -> the
//    logit phase's row-strided ds_read_b128 spreads across banks
//  - V linear (PV reads one row per 64 lanes: conflict-free already)
//  - logits: 16 x (3 ds_read_b128 + 8 fma) per (q,j) lane
//  - PV: packed u32 V reads, packed u32 bf16x2 stores
// ---------------------------------------------------------------------------
__device__ __forceinline__ int swz(int byte) {
    return byte ^ (((byte >> 8) & 7) << 4);
}

__global__ __launch_bounds__(256)
void attn_kernel(const __hip_bfloat16* __restrict__ Q,
                 const __hip_bfloat16* __restrict__ Kt,
                 const __hip_bfloat16* __restrict__ Vt,
                 const __hip_bfloat16* __restrict__ R,   // [24][1536] rel_k
                 __hip_bfloat16* __restrict__ O)
{
    const int tid = threadIdx.x;
    int idx = blockIdx.x;
    const int h = idx % NHEAD;  idx /= NHEAD;
    const int n = idx % NBLK;   idx /= NBLK;
    const int b = idx;                       // phase-local batch index

    __shared__ __align__(16) char qs[CHUNK * 256];   // 12 rows x 256B, swizzled
    __shared__ __align__(16) char ks[23 * 256];      // swizzled
    __shared__ __align__(16) char vs[23 * 256];      // linear
    __shared__ __align__(16) char rs[CHUNK * 256];   // rs[j]=rel_k[12-j], swz
    __shared__ float lg[CHUNK][CHUNK];

    const size_t rowbase = (size_t)b * SEQ + (size_t)n * CHUNK;
    const int hoff = h * HDIM;

    // ---- stage Q (192 chunks) + R (192 chunks), 16B each ----
    #pragma unroll
    for (int it = 0; it < 2; ++it) {
        int i = it * 256 + tid;
        if (i < 384) {
            if (i < 192) {
                int row = i >> 4, c = i & 15;
                uint4 v = *(const uint4*)(Q + (rowbase + row) * HID + hoff + c * 8);
                *(uint4*)(qs + swz(row * 256 + c * 16)) = v;
            } else {
                int t = i - 192;
                int j = t >> 4, c = t & 15;
                uint4 v = *(const uint4*)(R + (size_t)(12 - j) * HID + hoff + c * 8);
                *(uint4*)(rs + swz(j * 256 + c * 16)) = v;
            }
        }
    }
    // ---- stage K (368 chunks, swizzled) + V (368 chunks, linear) ----
    #pragma unroll
    for (int it = 0; it < 3; ++it) {
        int i = it * 256 + tid;
        if (i < 736) {
            int t = (i < 368) ? i : i - 368;
            int row = t >> 4, c = t & 15;
            int g = n * CHUNK + row - 11;
            uint4 v = make_uint4(0u, 0u, 0u, 0u);
            if (g >= 0) {
                v = *(const uint4*)(Kt + 0 * (size_t)HID +
                                    ((size_t)b * SEQ + g) * HID + hoff + c * 8);
                if (i >= 368)
                    v = *(const uint4*)(Vt + ((size_t)b * SEQ + g) * HID + hoff + c * 8);
            }
            if (i < 368)
                *(uint4*)(ks + swz(row * 256 + c * 16)) = v;
            else
                *(uint4*)(vs + t * 16) = v;
        }
    }
    __syncthreads();

    // ---- logits: lane (q,j) computes q . (k[q+11-j] + r[j]) ----
    if (tid < CHUNK * CHUNK) {
        int q = tid / CHUNK, j = tid - (tid / CHUNK) * CHUNK;
        bool valid = (n > 0) || (j <= q);
        float acc = 0.0f;
        if (valid) {
            int krow = q + 11 - j;
            #pragma unroll
            for (int c = 0; c < 16; ++c) {
                u16x8 qv = *(const u16x8*)(qs + swz(q * 256 + c * 16));
                u16x8 kv = *(const u16x8*)(ks + swz(krow * 256 + c * 16));
                u16x8 rv = *(const u16x8*)(rs + swz(j * 256 + c * 16));
                #pragma unroll
                for (int e = 0; e < 8; ++e)
                    acc += bf2f(qv[e]) * (bf2f(kv[e]) + bf2f(rv[e]));
            }
            acc = tanhf(acc * 0.02f) * 50.0f;
        }
        lg[q][j] = valid ? acc : -1e30f;
    }
    __syncthreads();

    // ---- softmax over j, per q row ----
    if (tid < CHUNK) {
        float m = -1e30f;
        #pragma unroll
        for (int j = 0; j < CHUNK; ++j) m = fmaxf(m, lg[tid][j]);
        float e[CHUNK];
        float s = 0.0f;
        #pragma unroll
        for (int j = 0; j < CHUNK; ++j) { e[j] = expf(lg[tid][j] - m); s += e[j]; }
        float inv = 1.0f / s;
        #pragma unroll
        for (int j = 0; j < CHUNK; ++j) lg[tid][j] = e[j] * inv;
    }
    __syncthreads();

    // ---- PV: 768 tasks, each (q, d-pair); V rows read as packed u32 ----
    #pragma unroll
    for (int it = 0; it < 3; ++it) {
        int i = it * 256 + tid;
        int q = i >> 6, dp = i & 63;
        float a0 = 0.0f, a1 = 0.0f;
        #pragma unroll
        for (int j = 0; j < CHUNK; ++j) {
            float p = lg[q][j];
            unsigned vv = *(const unsigned*)(vs + (q + 11 - j) * 256 + dp * 4);
            a0 += p * bf2f((unsigned short)(vv & 0xffffu));
            a1 += p * bf2f((unsigned short)(vv >> 16));
        }
        union { __hip_bfloat16 h[2]; unsigned u; } pk;
        pk.h[0] = __float2bfloat16(san(a0));
        pk.h[1] = __float2bfloat16(san(a1));
        *(unsigned*)(O + (rowbase + q) * HID + hoff + dp * 2) = pk.u;
    }
}

// ---------------------------------------------------------------------------
// ws layout: [qscale 1KB][Rk 72KB][posb 72KB][Wqkv 13.5MB][Wrelb 4.5MB]
//            [Wpostb 4.5MB][Qb][Kb]
// Xb and Vb live inside d_out (dead before post-GEMM writes that region).
// Attention output O aliases Qb.
// ---------------------------------------------------------------------------
extern "C" void kernel_launch(void* const* d_in, const int* in_sizes, int n_in,
                              void* d_out, int out_size, void* d_ws, size_t ws_size,
                              hipStream_t stream) {
    const float* x     = (const float*)d_in[0];
    const float* pos   = (const float*)d_in[1];
    const float* Wq    = (const float*)d_in[2];
    const float* Wk    = (const float*)d_in[3];
    const float* Wv    = (const float*)d_in[4];
    const float* Wrel  = (const float*)d_in[5];
    const float* Wpost = (const float*)d_in[6];
    const float* pds   = (const float*)d_in[7];
    float* out = (float*)d_out;

    char* ws = (char*)d_ws;
    float* qscale          = (float*)ws;                          // 1024 B
    __hip_bfloat16* Rk     = (__hip_bfloat16*)(ws + 1024);        // 73728 B
    __hip_bfloat16* posb   = (__hip_bfloat16*)(ws + 1024 + 73728);
    __hip_bfloat16* Wqkv   = (__hip_bfloat16*)(ws + 1024 + 2 * 73728);
    __hip_bfloat16* Wrelb  = Wqkv + (size_t)3 * 1536 * 1536;
    __hip_bfloat16* Wpostb = Wrelb + (size_t)1536 * 1536;
    __hip_bfloat16* Qb     = Wpostb + (size_t)1536 * 1536;
    const size_t fixed = 1024 + 2 * 73728 +
                         (size_t)5 * 1536 * 1536 * 2;             // 23,741,440
    const size_t qk_full = 2 * (size_t)MROWS * HID * 2;           // 147,456,000

    int phases;
    if      (ws_size >= fixed + qk_full)     phases = 1;
    else if (ws_size >= fixed + qk_full / 2) phases = 2;
    else                                     phases = 4;
    const int    Bp = BATCH / phases;
    const size_t Mp = (size_t)Bp * SEQ;
    __hip_bfloat16* Kb = Qb + Mp * HID;

    qscale_kernel<<<1, 128, 0, stream>>>(pds, qscale);
    convert_misc_kernel<<<dim3(2304, 6), 256, 0, stream>>>(
        Wq, Wk, Wv, Wrel, Wpost, pos, Wqkv, Wrelb, Wpostb, posb);
    gemm_rel<<<dim3(12, 1), 256, 0, stream>>>(posb, Wrelb, Rk, CTXW);

    for (int p = 0; p < phases; ++p) {
        __hip_bfloat16* Xb =
            (__hip_bfloat16*)((char*)d_out + p * Mp * HID * 4);
        __hip_bfloat16* Vb = Xb + Mp * HID;

        convert_x_kernel<<<2048, 256, 0, stream>>>(
            x + p * Mp * HID, Xb, (int)(Mp * HID / 4));
        gemm_qkv_bb<<<dim3(36, (unsigned)((Mp + 127) / 128)), 256, 0, stream>>>(
            Xb, Wqkv, Qb, Kb, Vb, qscale, (int)Mp);
        attn_kernel<<<Bp * NBLK * NHEAD, 256, 0, stream>>>(Qb, Kb, Vb, Rk, Qb);
        gemm_post<<<dim3(12, (unsigned)((Mp + 127) / 128)), 256, 0, stream>>>(
            Qb, Wpostb, out + p * Mp * HID, (int)Mp);
    }
}